// Round 5
// baseline (617.795 us; speedup 1.0000x reference)
//
#include <hip/hip_runtime.h>
#include <math.h>

#define BG   16
#define NPG  400
#define NN   (BG*NPG)      // 6400 nodes
#define KNN  20
#define NH   8
#define HD   16
#define EM   128
#define NL   3
#define NEGS 0.2f
#define BNEPS 1e-5f
#define MAXDEG 192
#define ROWW 16            // u32 words per adjacency row
#define NSLOT 7            // ceil(400/64) candidates per lane
#define GBLK 512           // grid blocks (<= 2 per CU co-resident, guaranteed)
#define TPB  256
#define GT   (GBLK*TPB)    // 131072 threads
#define NWAV (GBLK*4)      // 2048 waves
#define SPAD 16            // floats per BN-stat slot (64B padding vs atomic contention)

// ---- hand-rolled grid barrier (all GBLK blocks co-resident by construction) ----
__device__ __forceinline__ void gsync(unsigned* bar, unsigned target) {
    __syncthreads();
    if (threadIdx.x == 0) {
        __threadfence();   // release: flush this XCD's L2 (writes visible device-wide)
        __hip_atomic_fetch_add(bar, 1u, __ATOMIC_RELAXED, __HIP_MEMORY_SCOPE_AGENT);
        while (__hip_atomic_load(bar, __ATOMIC_RELAXED, __HIP_MEMORY_SCOPE_AGENT) < target)
            __builtin_amdgcn_s_sleep(1);
        __threadfence();   // acquire: invalidate stale L1/L2 lines
    }
    __syncthreads();
}

// ---- fused: [BN+ELU+residual of prev layer] + hh = h@W + score dots --------
__device__ __forceinline__ void mm_phase(
        float* __restrict__ h, const float* __restrict__ gout,
        const float* __restrict__ stat, const float* __restrict__ gamma,
        const float* __restrict__ beta, const float* __restrict__ w,
        const float* __restrict__ asrc, const float* __restrict__ adst,
        float* __restrict__ hh, float* __restrict__ ssrc, float* __restrict__ sdst,
        float* smem) {
    float (*hs)[EM] = (float(*)[EM])smem;
    int t = threadIdx.x;
    for (int tile = blockIdx.x; tile < NN / 16; tile += GBLK) {
        int row0 = tile * 16;
        for (int idx = t; idx < 16 * EM; idx += TPB) {
            int r = idx >> 7, c = idx & 127;
            size_t gi = (size_t)(row0 + r) * EM + c;
            float v;
            if (gout) {
                float m  = stat[c * SPAD] * (1.f / NN);
                float vr = stat[(128 + c) * SPAD] * (1.f / NN) - m * m;
                float bnv = (gout[gi] - m) * rsqrtf(vr + BNEPS) * gamma[c] + beta[c];
                bnv = bnv > 0.f ? bnv : expm1f(bnv);   // elu
                v = bnv + h[gi];                        // residual
                h[gi] = v;
            } else {
                v = h[gi];
            }
            hs[r][c] = v;
        }
        __syncthreads();
        int cc = t & 127, half = t >> 7;
        float acc[8] = {0, 0, 0, 0, 0, 0, 0, 0};
        const float* wp = w + cc;
        for (int k = 0; k < EM; k += 4) {
            float w0 = wp[(k + 0) * EM], w1 = wp[(k + 1) * EM];
            float w2 = wp[(k + 2) * EM], w3 = wp[(k + 3) * EM];
            #pragma unroll
            for (int rr = 0; rr < 8; ++rr) {
                const float4 hv = *(const float4*)&hs[half * 8 + rr][k];
                acc[rr] = fmaf(hv.x, w0, fmaf(hv.y, w1, fmaf(hv.z, w2, fmaf(hv.w, w3, acc[rr]))));
            }
        }
        #pragma unroll
        for (int rr = 0; rr < 8; ++rr)
            hh[(size_t)(row0 + half * 8 + rr) * EM + cc] = acc[rr];
        __syncthreads();
        #pragma unroll
        for (int rr = 0; rr < 8; ++rr) hs[half * 8 + rr][cc] = acc[rr];
        __syncthreads();
        if (t < 16 * NH) {
            int row = t >> 3, hd = t & 7;
            const float* ap = asrc + hd * HD;
            const float* dp = adst + hd * HD;
            float s1 = 0.f, s2 = 0.f;
            #pragma unroll
            for (int d = 0; d < HD; ++d) {
                float v = hs[row][hd * HD + d];
                s1 += v * ap[d]; s2 += v * dp[d];
            }
            ssrc[(size_t)(row0 + row) * NH + hd] = s1;
            sdst[(size_t)(row0 + row) * NH + hd] = s2;
        }
        __syncthreads();
    }
}

// ---- attention (wave-per-node, no block barriers) + fused BN-stat accum ----
__device__ __forceinline__ void attn_phase(
        const float* __restrict__ hh, const int* __restrict__ nbrl,
        const int* __restrict__ cnt, const float* __restrict__ ssrc,
        const float* __restrict__ sdst, const float* __restrict__ bias,
        float* __restrict__ gout, float* __restrict__ statl, float* smem) {
    int widb = threadIdx.x >> 6, lane = threadIdx.x & 63;
    float* sc = smem + widb * 1792;        // 1536 floats scores + 192 ints nbr
    int*   nb = (int*)(sc + 1536);
    float* red = smem + 4 * 1792;          // 256 floats block-stat partials
    int wid = blockIdx.x * 4 + widb;
    int h0 = lane >> 4;
    int hd = lane & 7, sub = lane >> 3;
    float s1a = 0.f, s2a = 0.f, s1b = 0.f, s2b = 0.f;

    for (int i = wid; i < NN; i += NWAV) {
        int c = cnt[i];
        for (int j = lane; j < c; j += 64) nb[j] = nbrl[(size_t)i * MAXDEG + j];
        asm volatile("s_waitcnt lgkmcnt(0)" ::: "memory");
        float sd = sdst[i * NH + hd];
        for (int idx = lane; idx < c * NH; idx += 64) {   // idx&7 == lane&7 (64%8==0)
            int jj = idx >> 3;
            float v = sd + ssrc[nb[jj] * NH + hd];
            sc[idx] = v >= 0.f ? v : NEGS * v;            // leaky_relu
        }
        asm volatile("s_waitcnt lgkmcnt(0)" ::: "memory");
        float mx = -INFINITY;
        for (int jj = sub; jj < c; jj += 8) mx = fmaxf(mx, sc[jj * 8 + hd]);
        #pragma unroll
        for (int off = 8; off < 64; off <<= 1) mx = fmaxf(mx, __shfl_xor(mx, off));
        float s = 0.f;
        for (int jj = sub; jj < c; jj += 8) {
            float e = expf(sc[jj * 8 + hd] - mx);
            sc[jj * 8 + hd] = e;
            s += e;
        }
        #pragma unroll
        for (int off = 8; off < 64; off <<= 1) s += __shfl_xor(s, off);
        float inv = 1.f / s;
        asm volatile("s_waitcnt lgkmcnt(0)" ::: "memory");
        float invh0 = __shfl(inv, h0);
        float invh1 = __shfl(inv, h0 + 4);
        float acc0 = 0.f, acc1 = 0.f;
        for (int jj = 0; jj < c; ++jj) {
            const float* hp = hh + (size_t)nb[jj] * EM;
            acc0 += sc[jj * 8 + h0] * hp[lane];
            acc1 += sc[jj * 8 + h0 + 4] * hp[lane + 64];
        }
        float v0 = acc0 * invh0 + bias[lane];
        float v1 = acc1 * invh1 + bias[lane + 64];
        gout[(size_t)i * EM + lane]      = v0;
        gout[(size_t)i * EM + lane + 64] = v1;
        s1a += v0; s2a += v0 * v0;
        s1b += v1; s2b += v1 * v1;
    }
    // block reduce of BN partials, then padded global atomics
    red[threadIdx.x] = 0.f;
    __syncthreads();
    atomicAdd(&red[lane], s1a);
    atomicAdd(&red[lane + 64], s1b);
    atomicAdd(&red[128 + lane], s2a);
    atomicAdd(&red[128 + lane + 64], s2b);
    __syncthreads();
    atomicAdd(&statl[threadIdx.x * SPAD], red[threadIdx.x]);
    __syncthreads();
}

__global__ __launch_bounds__(TPB, 2) void mega_kernel(
        unsigned* __restrict__ bar,
        const float* __restrict__ x, const float* __restrict__ pos,
        const float* __restrict__ pw, const float* __restrict__ pb,
        const float* __restrict__ lin_w, const float* __restrict__ asrc,
        const float* __restrict__ adst, const float* __restrict__ gbias,
        const float* __restrict__ gamma, const float* __restrict__ beta,
        float* __restrict__ out,
        unsigned* __restrict__ rowmask, int* __restrict__ nbrl, int* __restrict__ cnt,
        float* __restrict__ h, float* __restrict__ hh, float* __restrict__ gout,
        float* __restrict__ ssrc, float* __restrict__ sdst, float* __restrict__ stat) {
    __shared__ float smem[7424];   // 29.7 KB: max(mm 2048, attn 4*1792+256)
    int tid = blockIdx.x * TPB + threadIdx.x;

    // ---- P0: zero rowmask/stat/out-tail, input projection -----------------
    for (int idx = tid; idx < NN * ROWW; idx += GT) rowmask[idx] = 0u;
    for (int idx = tid; idx < NL * 256 * SPAD; idx += GT) stat[idx] = 0.f;
    if (tid < BG * EM) out[(size_t)NN * EM + tid] = 0.f;
    for (int idx = tid; idx < NN * EM; idx += GT) {
        int n = idx >> 7, c = idx & 127;
        h[idx] = x[n * 3 + 0] * pw[0 * EM + c] + x[n * 3 + 1] * pw[1 * EM + c]
               + x[n * 3 + 2] * pw[2 * EM + c] + pb[c];
    }
    gsync(bar, 1 * GBLK);

    // ---- P1: kNN (wave per node, register top-20) --------------------------
    {
        int wid = tid >> 6, lane = threadIdx.x & 63;
        for (int i = wid; i < NN; i += NWAV) {
            int g = i / NPG, li = i - g * NPG;
            const float* pg = pos + (size_t)g * NPG * 2;
            float xi = pg[li * 2], yi = pg[li * 2 + 1];
            float dl[NSLOT];
            #pragma unroll
            for (int s = 0; s < NSLOT; ++s) {
                int j = lane + (s << 6);
                if (j < NPG && j != li) {
                    float dx = __fsub_rn(xi, pg[j * 2]);
                    float dy = __fsub_rn(yi, pg[j * 2 + 1]);
                    dl[s] = __fadd_rn(__fmul_rn(dx, dx), __fmul_rn(dy, dy));  // exact np rounding
                } else {
                    dl[s] = INFINITY;
                }
            }
            int winj = -1;
            #pragma unroll 1
            for (int r = 0; r < KNN; ++r) {
                float bv = dl[0]; int bs = 0;
                #pragma unroll
                for (int s = 1; s < NSLOT; ++s)
                    if (dl[s] < bv) { bv = dl[s]; bs = s; }
                int bj = lane + (bs << 6);
                #pragma unroll
                for (int off = 32; off > 0; off >>= 1) {
                    float ov = __shfl_xor(bv, off);
                    int   oj = __shfl_xor(bj, off);
                    if (ov < bv || (ov == bv && oj < bj)) { bv = ov; bj = oj; }
                }
                if ((bj & 63) == lane) {
                    int s = bj >> 6;
                    #pragma unroll
                    for (int q = 0; q < NSLOT; ++q) if (q == s) dl[q] = INFINITY;
                }
                if (lane == r) winj = bj;
            }
            if (lane < KNN) {
                atomicOr(&rowmask[(size_t)i * ROWW + (winj >> 5)], 1u << (winj & 31));
                atomicOr(&rowmask[((size_t)g * NPG + winj) * ROWW + (li >> 5)], 1u << (li & 31));
            } else if (lane == KNN) {
                atomicOr(&rowmask[(size_t)i * ROWW + (li >> 5)], 1u << (li & 31));
            }
        }
    }
    gsync(bar, 2 * GBLK);

    // ---- P2: neighbor lists (thread per node) ------------------------------
    for (int i = tid; i < NN; i += GT) {
        int base = (i / NPG) * NPG;
        int c = 0;
        for (int wd = 0; wd < 13; ++wd) {
            unsigned m = rowmask[(size_t)i * ROWW + wd];
            while (m) {
                int b = __ffs(m) - 1;
                m &= m - 1;
                int j = wd * 32 + b;
                if (j < NPG && c < MAXDEG) nbrl[(size_t)i * MAXDEG + c++] = base + j;
            }
        }
        cnt[i] = c;
    }

    // ---- layers ------------------------------------------------------------
    for (int l = 0; l < NL; ++l) {
        int lp = l ? l - 1 : 0;
        mm_phase(h, l ? gout : nullptr, stat + (size_t)(l - 1) * 256 * SPAD,
                 gamma + (size_t)lp * EM, beta + (size_t)lp * EM,
                 lin_w + (size_t)l * EM * EM,
                 asrc + (size_t)l * EM, adst + (size_t)l * EM,
                 hh, ssrc, sdst, smem);
        gsync(bar, (unsigned)(3 + 2 * l) * GBLK);
        attn_phase(hh, nbrl, cnt, ssrc, sdst, gbias + (size_t)l * EM,
                   gout, stat + (size_t)l * 256 * SPAD, smem);
        gsync(bar, (unsigned)(4 + 2 * l) * GBLK);
    }

    // ---- P8: finish — BN+ELU+residual (layer 2) + node out + graph means ---
    {
        int b = blockIdx.x;               // 16 graphs x 32 chunks
        int g = b >> 5, ch = b & 31;
        int rows = ch < 16 ? 13 : 12;     // 16*13 + 16*12 = 400
        int r0 = ch * 12 + (ch < 16 ? ch : 16);
        int t = threadIdx.x, c = t & 127, half = t >> 7;
        const float* statl = stat + (size_t)2 * 256 * SPAD;
        float m  = statl[c * SPAD] * (1.f / NN);
        float vr = statl[(128 + c) * SPAD] * (1.f / NN) - m * m;
        float rs = rsqrtf(vr + BNEPS);
        float ga = gamma[2 * EM + c], be = beta[2 * EM + c];
        float s = 0.f;
        for (int k = half; k < rows; k += 2) {
            size_t gi = (size_t)(g * NPG + r0 + k) * EM + c;
            float v = (gout[gi] - m) * rs * ga + be;
            v = v > 0.f ? v : expm1f(v);
            v += h[gi];
            out[gi] = v;
            s += v;
        }
        float* l1 = smem;
        l1[t] = s;
        __syncthreads();
        if (half == 0)
            atomicAdd(&out[(size_t)NN * EM + g * EM + c], (l1[c] + l1[c + 128]) * (1.f / NPG));
    }
}

extern "C" void kernel_launch(void* const* d_in, const int* in_sizes, int n_in,
                              void* d_out, int out_size, void* d_ws, size_t ws_size,
                              hipStream_t stream) {
    const float* x      = (const float*)d_in[0];
    const float* pos    = (const float*)d_in[1];
    // d_in[2] = batch (int32), unused: graphs are contiguous blocks of 400
    const float* proj_w = (const float*)d_in[3];
    const float* proj_b = (const float*)d_in[4];
    const float* lin_w  = (const float*)d_in[5];
    const float* asrc   = (const float*)d_in[6];
    const float* adst   = (const float*)d_in[7];
    const float* gbias  = (const float*)d_in[8];
    const float* gamma  = (const float*)d_in[9];
    const float* beta   = (const float*)d_in[10];
    float* out = (float*)d_out;

    char* p = (char*)d_ws;
    auto take = [&](size_t bytes) { char* q = p; p += (bytes + 63) & ~(size_t)63; return q; };
    unsigned* bar     = (unsigned*)take(64);
    unsigned* rowmask = (unsigned*)take((size_t)NN * ROWW * 4);
    int*      nbrl    = (int*)take((size_t)NN * MAXDEG * 4);
    int*      cnt     = (int*)take((size_t)NN * 4);
    float*    h       = (float*)take((size_t)NN * EM * 4);
    float*    hh      = (float*)take((size_t)NN * EM * 4);
    float*    gout    = (float*)take((size_t)NN * EM * 4);
    float*    ssrc    = (float*)take((size_t)NN * NH * 4);
    float*    sdst    = (float*)take((size_t)NN * NH * 4);
    float*    stat    = (float*)take((size_t)NL * 256 * SPAD * 4);

    hipMemsetAsync(bar, 0, 64, stream);
    mega_kernel<<<GBLK, TPB, 0, stream>>>(bar, x, pos, proj_w, proj_b, lin_w,
                                          asrc, adst, gbias, gamma, beta, out,
                                          rowmask, nbrl, cnt, h, hh, gout,
                                          ssrc, sdst, stat);
}

// Round 6
// 210.737 us; speedup vs baseline: 2.9316x; 2.9316x over previous
//
#include <hip/hip_runtime.h>
#include <math.h>

#define BG   16
#define NPG  400
#define NN   (BG*NPG)      // 6400 nodes
#define KNN  20
#define NH   8
#define HD   16
#define EM   128
#define NL   3
#define NEGS 0.2f
#define BNEPS 1e-5f
#define MAXDEG 128
#define NSLOT 7            // ceil(400/64) candidates per lane
#define SPAD 16            // floats per BN-stat slot (64B anti-contention padding)

// ---------------- kNN: one wave per node, register top-20 -------------------
// Writes fwd[i][20] = local indices of the 20 nearest neighbors. No atomics.
__global__ __launch_bounds__(512) void knn_kernel(const float* __restrict__ pos,
                                                  int* __restrict__ fwd,
                                                  float* __restrict__ out) {
    if (blockIdx.x == 0)   // zero graph-mean output tail (16*128 floats)
        for (int idx = threadIdx.x; idx < BG * EM; idx += 512)
            out[(size_t)NN * EM + idx] = 0.f;

    int wave = threadIdx.x >> 6, lane = threadIdx.x & 63;
    int i = blockIdx.x * 8 + wave;      // global node
    int g = i / NPG, li = i - g * NPG;  // graph, local index
    const float* pg = pos + (size_t)g * NPG * 2;
    float xi = pg[li * 2], yi = pg[li * 2 + 1];

    float dl[NSLOT];
    #pragma unroll
    for (int s = 0; s < NSLOT; ++s) {
        int j = lane + (s << 6);
        if (j < NPG && j != li) {
            float dx = __fsub_rn(xi, pg[j * 2]);
            float dy = __fsub_rn(yi, pg[j * 2 + 1]);
            dl[s] = __fadd_rn(__fmul_rn(dx, dx), __fmul_rn(dy, dy));  // exact np rounding
        } else {
            dl[s] = INFINITY;
        }
    }

    int winj = 0;  // lane r (r<20) holds the r-th selected neighbor
    #pragma unroll 1
    for (int r = 0; r < KNN; ++r) {
        float bv = dl[0]; int bs = 0;
        #pragma unroll
        for (int s = 1; s < NSLOT; ++s)
            if (dl[s] < bv) { bv = dl[s]; bs = s; }
        int bj = lane + (bs << 6);
        #pragma unroll
        for (int off = 32; off > 0; off >>= 1) {
            float ov = __shfl_xor(bv, off);
            int   oj = __shfl_xor(bj, off);
            if (ov < bv || (ov == bv && oj < bj)) { bv = ov; bj = oj; }
        }
        if ((bj & 63) == lane) {
            int s = bj >> 6;
            #pragma unroll
            for (int q = 0; q < NSLOT; ++q) if (q == s) dl[q] = INFINITY;
        }
        if (lane == r) winj = bj;
    }
    if (lane < KNN) fwd[(size_t)i * KNN + lane] = winj;
}

// ---- undirected union + self loops via per-graph LDS bitmap (no global zero)
__global__ __launch_bounds__(1024) void nbr_kernel(const int* __restrict__ fwd,
                                                   int* __restrict__ nbr,
                                                   int* __restrict__ cnt,
                                                   float* __restrict__ out) {
    int g = blockIdx.x, t = threadIdx.x;
    __shared__ unsigned bm[NPG][16];     // 400 x 512 bits = 25.6 KB
    for (int idx = t; idx < NPG * 16; idx += 1024) ((unsigned*)bm)[idx] = 0u;
    if (t < 128) out[(size_t)NN * EM + g * EM + t] = 0.f;  // graph-mean tail zero
    __syncthreads();
    for (int e = t; e < NPG * KNN; e += 1024) {
        int src = e / KNN;
        int dst = fwd[(size_t)(g * NPG + src) * KNN + (e - src * KNN)];
        atomicOr(&bm[src][dst >> 5], 1u << (dst & 31));
        atomicOr(&bm[dst][src >> 5], 1u << (src & 31));
    }
    if (t < NPG) atomicOr(&bm[t][t >> 5], 1u << (t & 31));  // self loop
    __syncthreads();
    if (t < NPG) {
        int gi = g * NPG + t;
        int base = g * NPG;
        int c = 0;
        for (int w = 0; w < 13; ++w) {
            unsigned m = bm[t][w];
            while (m) {
                int b = __ffs(m) - 1;
                m &= m - 1;
                if (c < MAXDEG) nbr[(size_t)gi * MAXDEG + c++] = base + w * 32 + b;
            }
        }
        cnt[gi] = c;
    }
}

// ---- fused: [proj (l=0) | BN+ELU+residual (l>0)] + hh = h@W + score dots ---
// Block 0 zeroes this layer's BN stat accumulator.
__global__ __launch_bounds__(256) void mmscore_kernel(
        float* __restrict__ h, const float* __restrict__ gout,
        const float* __restrict__ stat, const float* __restrict__ gamma,
        const float* __restrict__ beta, const float* __restrict__ x,
        const float* __restrict__ pw, const float* __restrict__ pb,
        const float* __restrict__ w,
        const float* __restrict__ asrc, const float* __restrict__ adst,
        float* __restrict__ hh, float* __restrict__ ssrc, float* __restrict__ sdst,
        float* __restrict__ statz) {
    __shared__ float hs[16][EM];
    int row0 = blockIdx.x * 16;
    int t = threadIdx.x;
    if (blockIdx.x == 0) statz[t * SPAD] = 0.f;

    for (int idx = t; idx < 16 * EM; idx += 256) {
        int r = idx >> 7, c = idx & 127;
        size_t gi = (size_t)(row0 + r) * EM + c;
        float v;
        if (gout) {
            float m  = stat[c * SPAD] * (1.f / NN);
            float vr = stat[(128 + c) * SPAD] * (1.f / NN) - m * m;
            float bnv = (gout[gi] - m) * rsqrtf(vr + BNEPS) * gamma[c] + beta[c];
            bnv = bnv > 0.f ? bnv : expm1f(bnv);       // elu
            v = bnv + h[gi];                           // residual
        } else {
            int n = row0 + r;                          // input projection
            v = x[n * 3 + 0] * pw[0 * EM + c] + x[n * 3 + 1] * pw[1 * EM + c]
              + x[n * 3 + 2] * pw[2 * EM + c] + pb[c];
        }
        h[gi] = v;
        hs[r][c] = v;
    }
    __syncthreads();

    int cc = t & 127, half = t >> 7;
    float acc[8] = {0, 0, 0, 0, 0, 0, 0, 0};
    const float* wp = w + cc;
    for (int k = 0; k < EM; k += 4) {
        float w0 = wp[(k + 0) * EM], w1 = wp[(k + 1) * EM];
        float w2 = wp[(k + 2) * EM], w3 = wp[(k + 3) * EM];
        #pragma unroll
        for (int rr = 0; rr < 8; ++rr) {
            const float4 hv = *(const float4*)&hs[half * 8 + rr][k];
            acc[rr] = fmaf(hv.x, w0, fmaf(hv.y, w1, fmaf(hv.z, w2, fmaf(hv.w, w3, acc[rr]))));
        }
    }
    #pragma unroll
    for (int rr = 0; rr < 8; ++rr)
        hh[(size_t)(row0 + half * 8 + rr) * EM + cc] = acc[rr];
    __syncthreads();
    #pragma unroll
    for (int rr = 0; rr < 8; ++rr) hs[half * 8 + rr][cc] = acc[rr];
    __syncthreads();
    if (t < 16 * NH) {
        int row = t >> 3, hd = t & 7;
        const float* ap = asrc + hd * HD;
        const float* dp = adst + hd * HD;
        float s1 = 0.f, s2 = 0.f;
        #pragma unroll
        for (int d = 0; d < HD; ++d) {
            float v = hs[row][hd * HD + d];
            s1 += v * ap[d]; s2 += v * dp[d];
        }
        ssrc[(size_t)(row0 + row) * NH + hd] = s1;
        sdst[(size_t)(row0 + row) * NH + hd] = s2;
    }
}

// ---- attention (wave per node) + fused BN-stat accumulation ----------------
__global__ __launch_bounds__(512) void attn_kernel(const float* __restrict__ hh,
                                                   const int* __restrict__ nbrl,
                                                   const int* __restrict__ cnt,
                                                   const float* __restrict__ ssrc,
                                                   const float* __restrict__ sdst,
                                                   const float* __restrict__ bias,
                                                   float* __restrict__ gout,
                                                   float* __restrict__ statl) {
    __shared__ float smem[8 * 1152 + 256];   // per-wave: 1024 scores + 128 nbr ints
    int widb = threadIdx.x >> 6, lane = threadIdx.x & 63;
    float* sc = smem + widb * 1152;
    int*   nb = (int*)(sc + 1024);
    float* red = smem + 8 * 1152;
    int i = blockIdx.x * 8 + widb;          // one node per wave, exact cover

    red[threadIdx.x & 255] = 0.f;           // zero stat partials (256 slots)
    __syncthreads();

    int c = cnt[i];
    for (int j = lane; j < c; j += 64) nb[j] = nbrl[(size_t)i * MAXDEG + j];
    asm volatile("s_waitcnt lgkmcnt(0)" ::: "memory");
    int hd = lane & 7, sub = lane >> 3;
    float sd = sdst[i * NH + hd];
    for (int idx = lane; idx < c * NH; idx += 64) {   // idx&7 == lane&7
        int jj = idx >> 3;
        float v = sd + ssrc[nb[jj] * NH + hd];
        sc[idx] = v >= 0.f ? v : NEGS * v;            // leaky_relu
    }
    asm volatile("s_waitcnt lgkmcnt(0)" ::: "memory");
    float mx = -INFINITY;
    for (int jj = sub; jj < c; jj += 8) mx = fmaxf(mx, sc[jj * 8 + hd]);
    #pragma unroll
    for (int off = 8; off < 64; off <<= 1) mx = fmaxf(mx, __shfl_xor(mx, off));
    float s = 0.f;
    for (int jj = sub; jj < c; jj += 8) {
        float e = expf(sc[jj * 8 + hd] - mx);
        sc[jj * 8 + hd] = e;
        s += e;
    }
    #pragma unroll
    for (int off = 8; off < 64; off <<= 1) s += __shfl_xor(s, off);
    float inv = 1.f / s;
    asm volatile("s_waitcnt lgkmcnt(0)" ::: "memory");
    int h0 = lane >> 4;
    float invh0 = __shfl(inv, h0);
    float invh1 = __shfl(inv, h0 + 4);
    float acc0 = 0.f, acc1 = 0.f;
    for (int jj = 0; jj < c; ++jj) {
        const float* hp = hh + (size_t)nb[jj] * EM;
        acc0 += sc[jj * 8 + h0] * hp[lane];
        acc1 += sc[jj * 8 + h0 + 4] * hp[lane + 64];
    }
    float v0 = acc0 * invh0 + bias[lane];
    float v1 = acc1 * invh1 + bias[lane + 64];
    gout[(size_t)i * EM + lane]      = v0;
    gout[(size_t)i * EM + lane + 64] = v1;

    // BN stat partials: channels lane (v0) and lane+64 (v1)
    atomicAdd(&red[lane], v0);
    atomicAdd(&red[lane + 64], v1);
    atomicAdd(&red[128 + lane], v0 * v0);
    atomicAdd(&red[192 + lane], v1 * v1);
    __syncthreads();
    if (threadIdx.x < 256)
        atomicAdd(&statl[threadIdx.x * SPAD], red[threadIdx.x]);
}

// ---- final: BN+ELU+residual (layer 2) -> node out + graph-mean atomics -----
__global__ __launch_bounds__(256) void finish_kernel(const float* __restrict__ gout,
                                                     const float* __restrict__ stat,
                                                     const float* __restrict__ gamma,
                                                     const float* __restrict__ beta,
                                                     const float* __restrict__ h,
                                                     float* __restrict__ out) {
    int b = blockIdx.x;          // 16 graphs x 8 chunks of 50 rows
    int g = b >> 3, ch = b & 7;
    int t = threadIdx.x, c = t & 127, half = t >> 7;
    float m  = stat[c * SPAD] * (1.f / NN);
    float vr = stat[(128 + c) * SPAD] * (1.f / NN) - m * m;
    float rs = rsqrtf(vr + BNEPS);
    float ga = gamma[c], be = beta[c];
    int r0 = g * NPG + ch * 50;
    float s = 0.f;
    for (int k = half; k < 50; k += 2) {
        size_t gi = (size_t)(r0 + k) * EM + c;
        float v = (gout[gi] - m) * rs * ga + be;
        v = v > 0.f ? v : expm1f(v);
        v += h[gi];
        out[gi] = v;
        s += v;
    }
    __shared__ float l1[256];
    l1[t] = s;
    __syncthreads();
    if (half == 0)
        atomicAdd(&out[(size_t)NN * EM + g * EM + c], (l1[c] + l1[c + 128]) * (1.f / NPG));
}

extern "C" void kernel_launch(void* const* d_in, const int* in_sizes, int n_in,
                              void* d_out, int out_size, void* d_ws, size_t ws_size,
                              hipStream_t stream) {
    const float* x      = (const float*)d_in[0];
    const float* pos    = (const float*)d_in[1];
    // d_in[2] = batch (int32), unused: graphs are contiguous blocks of 400
    const float* proj_w = (const float*)d_in[3];
    const float* proj_b = (const float*)d_in[4];
    const float* lin_w  = (const float*)d_in[5];
    const float* asrc   = (const float*)d_in[6];
    const float* adst   = (const float*)d_in[7];
    const float* gbias  = (const float*)d_in[8];
    const float* gamma  = (const float*)d_in[9];
    const float* beta   = (const float*)d_in[10];
    float* out = (float*)d_out;

    char* p = (char*)d_ws;
    auto take = [&](size_t bytes) { char* q = p; p += (bytes + 63) & ~(size_t)63; return q; };
    int*   fwd  = (int*)take((size_t)NN * KNN * 4);
    int*   nbrl = (int*)take((size_t)NN * MAXDEG * 4);
    int*   cnt  = (int*)take((size_t)NN * 4);
    float* h    = (float*)take((size_t)NN * EM * 4);
    float* hh   = (float*)take((size_t)NN * EM * 4);
    float* gout = (float*)take((size_t)NN * EM * 4);
    float* ssrc = (float*)take((size_t)NN * NH * 4);
    float* sdst = (float*)take((size_t)NN * NH * 4);
    float* statA = (float*)take((size_t)256 * SPAD * 4);
    float* statB = (float*)take((size_t)256 * SPAD * 4);
    float* statv[2] = {statA, statB};

    knn_kernel<<<NN / 8, 512, 0, stream>>>(pos, fwd, out);
    nbr_kernel<<<BG, 1024, 0, stream>>>(fwd, nbrl, cnt, out);

    for (int l = 0; l < NL; ++l) {
        float* statz = statv[l & 1];
        const float* statp = statv[(l + 1) & 1];
        int lp = l ? l - 1 : 0;
        mmscore_kernel<<<NN / 16, 256, 0, stream>>>(
            h, l ? gout : nullptr, statp,
            gamma + (size_t)lp * EM, beta + (size_t)lp * EM,
            x, proj_w, proj_b,
            lin_w + (size_t)l * EM * EM, asrc + (size_t)l * EM, adst + (size_t)l * EM,
            hh, ssrc, sdst, statz);
        attn_kernel<<<NN / 8, 512, 0, stream>>>(hh, nbrl, cnt, ssrc, sdst,
                                                gbias + (size_t)l * EM, gout,
                                                statv[l & 1]);
    }

    finish_kernel<<<BG * 8, 256, 0, stream>>>(gout, statv[0],
                                              gamma + (size_t)2 * EM, beta + (size_t)2 * EM,
                                              h, out);
}

// Round 7
// 207.961 us; speedup vs baseline: 2.9707x; 1.0133x over previous
//
#include <hip/hip_runtime.h>
#include <math.h>

#define BG   16
#define NPG  400
#define NN   (BG*NPG)      // 6400 nodes
#define KNN  20
#define NH   8
#define HD   16
#define EM   128
#define NL   3
#define NEGS 0.2f
#define BNEPS 1e-5f
#define MAXDEG 128
#define NSLOT 7            // ceil(400/64) candidates per lane
#define SPAD 16            // floats per BN-stat slot (64B anti-contention padding)
#define KNB  800           // knn blocks inside k1 (8 nodes each)
#define MMB  200           // mm tiles (32 rows each)

// ---------------- kNN body: one wave per node, register top-20 --------------
__device__ __forceinline__ void knn_body(const float* __restrict__ pos,
                                         int* __restrict__ fwd, int bid) {
    int wave = threadIdx.x >> 6, lane = threadIdx.x & 63;
    int i = bid * 8 + wave;             // global node
    int g = i / NPG, li = i - g * NPG;  // graph, local index
    const float* pg = pos + (size_t)g * NPG * 2;
    float xi = pg[li * 2], yi = pg[li * 2 + 1];

    float dl[NSLOT];
    #pragma unroll
    for (int s = 0; s < NSLOT; ++s) {
        int j = lane + (s << 6);
        if (j < NPG && j != li) {
            float dx = __fsub_rn(xi, pg[j * 2]);
            float dy = __fsub_rn(yi, pg[j * 2 + 1]);
            dl[s] = __fadd_rn(__fmul_rn(dx, dx), __fmul_rn(dy, dy));  // exact np rounding
        } else {
            dl[s] = INFINITY;
        }
    }
    int winj = 0;  // lane r (r<20) holds the r-th selected neighbor
    #pragma unroll 1
    for (int r = 0; r < KNN; ++r) {
        float bv = dl[0]; int bs = 0;
        #pragma unroll
        for (int s = 1; s < NSLOT; ++s)
            if (dl[s] < bv) { bv = dl[s]; bs = s; }
        int bj = lane + (bs << 6);
        #pragma unroll
        for (int off = 32; off > 0; off >>= 1) {
            float ov = __shfl_xor(bv, off);
            int   oj = __shfl_xor(bj, off);
            if (ov < bv || (ov == bv && oj < bj)) { bv = ov; bj = oj; }
        }
        if ((bj & 63) == lane) {
            int s = bj >> 6;
            #pragma unroll
            for (int q = 0; q < NSLOT; ++q) if (q == s) dl[q] = INFINITY;
        }
        if (lane == r) winj = bj;
    }
    if (lane < KNN) fwd[(size_t)i * KNN + lane] = winj;
}

// ---- mm tile (32 rows): [proj | BN+ELU+residual] + hh = h@W + score dots ---
__device__ __forceinline__ void mm_tile(
        int tile, float* __restrict__ h, const float* __restrict__ gout,
        const float* __restrict__ stat, const float* __restrict__ gamma,
        const float* __restrict__ beta, const float* __restrict__ x,
        const float* __restrict__ pw, const float* __restrict__ pb,
        const float* __restrict__ w,
        const float* __restrict__ asrc, const float* __restrict__ adst,
        float* __restrict__ hh, float* __restrict__ ssrc, float* __restrict__ sdst,
        float (*hs)[EM]) {
    int t = threadIdx.x;               // 0..511
    int row0 = tile * 32;
    for (int idx = t; idx < 32 * EM; idx += 512) {
        int r = idx >> 7, c = idx & 127;
        size_t gi = (size_t)(row0 + r) * EM + c;
        float v;
        if (gout) {
            float m  = stat[c * SPAD] * (1.f / NN);
            float vr = stat[(128 + c) * SPAD] * (1.f / NN) - m * m;
            float bnv = (gout[gi] - m) * rsqrtf(vr + BNEPS) * gamma[c] + beta[c];
            bnv = bnv > 0.f ? bnv : expm1f(bnv);   // elu
            v = bnv + h[gi];                        // residual
        } else {
            int n = row0 + r;                       // input projection
            v = x[n * 3 + 0] * pw[c] + x[n * 3 + 1] * pw[EM + c]
              + x[n * 3 + 2] * pw[2 * EM + c] + pb[c];
        }
        h[gi] = v;
        hs[r][c] = v;
    }
    __syncthreads();
    int cc = t & 127, q = t >> 7;
    float acc[8] = {0, 0, 0, 0, 0, 0, 0, 0};
    const float* wp = w + cc;
    for (int k = 0; k < EM; k += 4) {
        float w0 = wp[(k + 0) * EM], w1 = wp[(k + 1) * EM];
        float w2 = wp[(k + 2) * EM], w3 = wp[(k + 3) * EM];
        #pragma unroll
        for (int rr = 0; rr < 8; ++rr) {
            const float4 hv = *(const float4*)&hs[q * 8 + rr][k];
            acc[rr] = fmaf(hv.x, w0, fmaf(hv.y, w1, fmaf(hv.z, w2, fmaf(hv.w, w3, acc[rr]))));
        }
    }
    #pragma unroll
    for (int rr = 0; rr < 8; ++rr)
        hh[(size_t)(row0 + q * 8 + rr) * EM + cc] = acc[rr];
    __syncthreads();
    #pragma unroll
    for (int rr = 0; rr < 8; ++rr) hs[q * 8 + rr][cc] = acc[rr];
    __syncthreads();
    if (t < 32 * NH) {
        int row = t >> 3, hd = t & 7;
        const float* ap = asrc + hd * HD;
        const float* dp = adst + hd * HD;
        float s1 = 0.f, s2 = 0.f;
        #pragma unroll
        for (int d = 0; d < HD; ++d) {
            float v = hs[row][hd * HD + d];
            s1 += v * ap[d]; s2 += v * dp[d];
        }
        ssrc[(size_t)(row0 + row) * NH + hd] = s1;
        sdst[(size_t)(row0 + row) * NH + hd] = s2;
    }
}

// ---- kernel 1: kNN (blocks 0..799)  ||  layer-0 mm (blocks 800..999) -------
__global__ __launch_bounds__(512) void k1_kernel(
        const float* __restrict__ pos, int* __restrict__ fwd,
        float* __restrict__ h, const float* __restrict__ x,
        const float* __restrict__ pw, const float* __restrict__ pb,
        const float* __restrict__ w0,
        const float* __restrict__ asrc0, const float* __restrict__ adst0,
        float* __restrict__ hh, float* __restrict__ ssrc, float* __restrict__ sdst,
        float* __restrict__ statz) {
    __shared__ float hs[32][EM];
    int bid = blockIdx.x;
    if (bid < KNB) {
        knn_body(pos, fwd, bid);
    } else {
        int tile = bid - KNB;
        if (tile == 0 && threadIdx.x < 256) statz[threadIdx.x * SPAD] = 0.f;
        mm_tile(tile, h, nullptr, nullptr, nullptr, nullptr,
                x, pw, pb, w0, asrc0, adst0, hh, ssrc, sdst, hs);
    }
}

// ---- mm kernel for layers 1,2 (zeroes next stat accumulator) ---------------
__global__ __launch_bounds__(512) void mm_kernel(
        float* __restrict__ h, const float* __restrict__ gout,
        const float* __restrict__ stat, const float* __restrict__ gamma,
        const float* __restrict__ beta, const float* __restrict__ w,
        const float* __restrict__ asrc, const float* __restrict__ adst,
        float* __restrict__ hh, float* __restrict__ ssrc, float* __restrict__ sdst,
        float* __restrict__ statz) {
    __shared__ float hs[32][EM];
    if (blockIdx.x == 0 && threadIdx.x < 256) statz[threadIdx.x * SPAD] = 0.f;
    mm_tile(blockIdx.x, h, gout, stat, gamma, beta,
            nullptr, nullptr, nullptr, w, asrc, adst, hh, ssrc, sdst, hs);
}

// ---- undirected union + self loops via per-graph LDS bitmap ----------------
__global__ __launch_bounds__(1024) void nbr_kernel(const int* __restrict__ fwd,
                                                   int* __restrict__ nbr,
                                                   int* __restrict__ cnt,
                                                   float* __restrict__ out) {
    int g = blockIdx.x, t = threadIdx.x;
    __shared__ unsigned bm[NPG][16];     // 400 x 512 bits = 25.6 KB
    for (int idx = t; idx < NPG * 16; idx += 1024) ((unsigned*)bm)[idx] = 0u;
    if (t < 128) out[(size_t)NN * EM + g * EM + t] = 0.f;  // zero graph-mean tail
    __syncthreads();
    for (int e = t; e < NPG * KNN; e += 1024) {
        int src = e / KNN;
        int dst = fwd[(size_t)(g * NPG + src) * KNN + (e - src * KNN)];
        atomicOr(&bm[src][dst >> 5], 1u << (dst & 31));
        atomicOr(&bm[dst][src >> 5], 1u << (src & 31));
    }
    if (t < NPG) atomicOr(&bm[t][t >> 5], 1u << (t & 31));  // self loop
    __syncthreads();
    if (t < NPG) {
        int gi = g * NPG + t;
        int base = g * NPG;
        int c = 0;
        for (int w = 0; w < 13; ++w) {
            unsigned m = bm[t][w];
            while (m) {
                int b = __ffs(m) - 1;
                m &= m - 1;
                if (c < MAXDEG) nbr[(size_t)gi * MAXDEG + c++] = base + w * 32 + b;
            }
        }
        cnt[gi] = c;
    }
}

// ---- attention (wave per node, float2 channels) + fused BN-stat accum ------
__global__ __launch_bounds__(512) void attn_kernel(const float* __restrict__ hh,
                                                   const int* __restrict__ nbrl,
                                                   const int* __restrict__ cnt,
                                                   const float* __restrict__ ssrc,
                                                   const float* __restrict__ sdst,
                                                   const float* __restrict__ bias,
                                                   float* __restrict__ gout,
                                                   float* __restrict__ statl) {
    __shared__ float smem[8 * 1152 + 256];   // per-wave: 1024 scores + 128 nbr ints
    int widb = threadIdx.x >> 6, lane = threadIdx.x & 63;
    float* sc = smem + widb * 1152;
    int*   nb = (int*)(sc + 1024);
    float* red = smem + 8 * 1152;
    int i = blockIdx.x * 8 + widb;           // one node per wave, exact cover

    if (threadIdx.x < 256) red[threadIdx.x] = 0.f;
    __syncthreads();

    int c = cnt[i];
    for (int j = lane; j < c; j += 64) nb[j] = nbrl[(size_t)i * MAXDEG + j];
    asm volatile("s_waitcnt lgkmcnt(0)" ::: "memory");
    int hd = lane & 7, sub = lane >> 3;
    float sd = sdst[i * NH + hd];
    for (int idx = lane; idx < c * NH; idx += 64) {   // idx&7 == lane&7
        int jj = idx >> 3;
        float v = sd + ssrc[nb[jj] * NH + hd];
        sc[idx] = v >= 0.f ? v : NEGS * v;            // leaky_relu
    }
    asm volatile("s_waitcnt lgkmcnt(0)" ::: "memory");
    float mx = -INFINITY;
    for (int jj = sub; jj < c; jj += 8) mx = fmaxf(mx, sc[jj * 8 + hd]);
    #pragma unroll
    for (int off = 8; off < 64; off <<= 1) mx = fmaxf(mx, __shfl_xor(mx, off));
    float s = 0.f;
    for (int jj = sub; jj < c; jj += 8) {
        float e = expf(sc[jj * 8 + hd] - mx);
        sc[jj * 8 + hd] = e;
        s += e;
    }
    #pragma unroll
    for (int off = 8; off < 64; off <<= 1) s += __shfl_xor(s, off);
    float inv = 1.f / s;                     // lane k (k<8) holds inv for head k
    asm volatile("s_waitcnt lgkmcnt(0)" ::: "memory");

    // PV: lane owns channels (2*lane, 2*lane+1); both in head h0 = lane>>3
    int h0 = lane >> 3;
    float invh = __shfl(inv, h0);
    float acc0 = 0.f, acc1 = 0.f;
    for (int jj = 0; jj < c; jj += 2) {
        float a0 = sc[jj * 8 + h0];
        float2 p0 = *(const float2*)(hh + (size_t)nb[jj] * EM + 2 * lane);
        int j1 = (jj + 1 < c) ? jj + 1 : jj;
        float a1 = (jj + 1 < c) ? sc[(jj + 1) * 8 + h0] : 0.f;
        float2 p1 = *(const float2*)(hh + (size_t)nb[j1] * EM + 2 * lane);
        acc0 += a0 * p0.x + a1 * p1.x;
        acc1 += a0 * p0.y + a1 * p1.y;
    }
    float2 bv = *(const float2*)(bias + 2 * lane);
    float v0 = acc0 * invh + bv.x;
    float v1 = acc1 * invh + bv.y;
    float2 ov; ov.x = v0; ov.y = v1;
    *(float2*)(gout + (size_t)i * EM + 2 * lane) = ov;

    // BN stat partials: channels 2*lane (v0), 2*lane+1 (v1)
    atomicAdd(&red[2 * lane], v0);
    atomicAdd(&red[2 * lane + 1], v1);
    atomicAdd(&red[128 + 2 * lane], v0 * v0);
    atomicAdd(&red[128 + 2 * lane + 1], v1 * v1);
    __syncthreads();
    if (threadIdx.x < 256)
        atomicAdd(&statl[threadIdx.x * SPAD], red[threadIdx.x]);
}

// ---- final: BN+ELU+residual (layer 2) -> node out + graph-mean atomics -----
__global__ __launch_bounds__(256) void finish_kernel(const float* __restrict__ gout,
                                                     const float* __restrict__ stat,
                                                     const float* __restrict__ gamma,
                                                     const float* __restrict__ beta,
                                                     const float* __restrict__ h,
                                                     float* __restrict__ out) {
    int b = blockIdx.x;          // 16 graphs x 8 chunks of 50 rows
    int g = b >> 3, ch = b & 7;
    int t = threadIdx.x, c = t & 127, half = t >> 7;
    float m  = stat[c * SPAD] * (1.f / NN);
    float vr = stat[(128 + c) * SPAD] * (1.f / NN) - m * m;
    float rs = rsqrtf(vr + BNEPS);
    float ga = gamma[c], be = beta[c];
    int r0 = g * NPG + ch * 50;
    float s = 0.f;
    for (int k = half; k < 50; k += 2) {
        size_t gi = (size_t)(r0 + k) * EM + c;
        float v = (gout[gi] - m) * rs * ga + be;
        v = v > 0.f ? v : expm1f(v);
        v += h[gi];
        out[gi] = v;
        s += v;
    }
    __shared__ float l1[256];
    l1[t] = s;
    __syncthreads();
    if (half == 0)
        atomicAdd(&out[(size_t)NN * EM + g * EM + c], (l1[c] + l1[c + 128]) * (1.f / NPG));
}

extern "C" void kernel_launch(void* const* d_in, const int* in_sizes, int n_in,
                              void* d_out, int out_size, void* d_ws, size_t ws_size,
                              hipStream_t stream) {
    const float* x      = (const float*)d_in[0];
    const float* pos    = (const float*)d_in[1];
    // d_in[2] = batch (int32), unused: graphs are contiguous blocks of 400
    const float* proj_w = (const float*)d_in[3];
    const float* proj_b = (const float*)d_in[4];
    const float* lin_w  = (const float*)d_in[5];
    const float* asrc   = (const float*)d_in[6];
    const float* adst   = (const float*)d_in[7];
    const float* gbias  = (const float*)d_in[8];
    const float* gamma  = (const float*)d_in[9];
    const float* beta   = (const float*)d_in[10];
    float* out = (float*)d_out;

    char* p = (char*)d_ws;
    auto take = [&](size_t bytes) { char* q = p; p += (bytes + 63) & ~(size_t)63; return q; };
    int*   fwd  = (int*)take((size_t)NN * KNN * 4);
    int*   nbrl = (int*)take((size_t)NN * MAXDEG * 4);
    int*   cnt  = (int*)take((size_t)NN * 4);
    float* h    = (float*)take((size_t)NN * EM * 4);
    float* hh   = (float*)take((size_t)NN * EM * 4);
    float* gout = (float*)take((size_t)NN * EM * 4);
    float* ssrc = (float*)take((size_t)NN * NH * 4);
    float* sdst = (float*)take((size_t)NN * NH * 4);
    float* statA = (float*)take((size_t)256 * SPAD * 4);
    float* statB = (float*)take((size_t)256 * SPAD * 4);
    float* statv[2] = {statA, statB};

    // 1: kNN || layer-0 mm (+zero statv[0])
    k1_kernel<<<KNB + MMB, 512, 0, stream>>>(pos, fwd, h, x, proj_w, proj_b,
                                             lin_w, asrc, adst, hh, ssrc, sdst,
                                             statv[0]);
    // 2: adjacency lists (+zero out tail)
    nbr_kernel<<<BG, 1024, 0, stream>>>(fwd, nbrl, cnt, out);
    // 3: attn layer 0 -> statv[0]
    attn_kernel<<<NN / 8, 512, 0, stream>>>(hh, nbrl, cnt, ssrc, sdst,
                                            gbias, gout, statv[0]);
    // 4: mm layer 1 (reads statv[0], zeroes statv[1])
    mm_kernel<<<MMB, 512, 0, stream>>>(h, gout, statv[0], gamma, beta,
                                       lin_w + (size_t)EM * EM, asrc + EM, adst + EM,
                                       hh, ssrc, sdst, statv[1]);
    // 5: attn layer 1 -> statv[1]
    attn_kernel<<<NN / 8, 512, 0, stream>>>(hh, nbrl, cnt, ssrc, sdst,
                                            gbias + EM, gout, statv[1]);
    // 6: mm layer 2 (reads statv[1], zeroes statv[0])
    mm_kernel<<<MMB, 512, 0, stream>>>(h, gout, statv[1], gamma + EM, beta + EM,
                                       lin_w + (size_t)2 * EM * EM, asrc + 2 * EM, adst + 2 * EM,
                                       hh, ssrc, sdst, statv[0]);
    // 7: attn layer 2 -> statv[0]
    attn_kernel<<<NN / 8, 512, 0, stream>>>(hh, nbrl, cnt, ssrc, sdst,
                                            gbias + 2 * EM, gout, statv[0]);
    // 8: finish
    finish_kernel<<<BG * 8, 256, 0, stream>>>(gout, statv[0],
                                              gamma + 2 * EM, beta + 2 * EM, h, out);
}